// Round 8
// baseline (233.589 us; speedup 1.0000x reference)
//
#include <hip/hip_runtime.h>
#include <hip/hip_cooperative_groups.h>

namespace cg = cooperative_groups;

// ---------------------------------------------------------------------------
// ActorCritic fused loss, MI355X.  T=8192, B=4096.
// ONE cooperative kernel, ONE pass over the data:
//   probe : every block tests the same 16KB mask prefix (word&0xFFFFFF00)
//           -> int32 {0,1} vs 1-byte bool layout. Deterministic.
//   phase1: fused pass over all 5 streams with LOCAL G (3-stage register
//           pipeline, 15 loads in flight/wave). Accumulates 10 sums + 5
//           carry-correction coefficient float4s (REGISTERS, persist across
//           grid.sync). Writes only chunk sums S[256][B4] (4 MiB).
//   phase2: fold S -> 16 group aggregates Sg (blocks 0..63)
//   phase3: backward scan Sg -> group carries Hg (blocks 0..3, 16 steps)
//   phase4: each block reconstructs its chunk carry H (<=15 S rows + Hg),
//           applies register corrections in f64, block-reduces -> partials
//   phase5: block 0 reduces partials, closed-form losses.
// Fallback (coop gate/launch refusal): proven 4-dispatch pipeline (r7).
// All FP orders fixed -> bitwise deterministic across replays.
// ---------------------------------------------------------------------------

constexpr int T     = 8192;
constexpr int B     = 4096;
constexpr int B4    = B / 4;          // 1024 float4 columns
constexpr int BLK   = 256;
constexpr int WAVES = BLK / 64;
constexpr int L     = 32;             // chunk length
constexpr int NC    = T / L;          // 256 chunks
constexpr int NTILE = NC * 4;         // 1024 blocks (4 column slices)
constexpr int GSZ   = 16;             // chunks per group
constexpr int NGRP  = NC / GSZ;       // 16 groups

constexpr float GAMMA_F = 0.99f;
constexpr double cpow(double g, int n) { double r = 1.0; for (int i = 0; i < n; ++i) r *= g; return r; }
constexpr float G32  = (float)cpow(0.99, L);        // gamma^32
constexpr float G512 = (float)cpow(0.99, L * GSZ);  // gamma^512

// --------------------------------------------------------------------------
// Per-component accumulate: 10 base sums (local G) + 5 correction coeffs.
#define COMPC(MJ, GX, RX, VX, LX, ZX, C0X, C1X, C2X, C3X, C4X)   \
    do {                                                         \
        GX = fmaf(GAMMA_F, GX, RX);                              \
        float mm = (MJ);                                         \
        float Gm = mm * GX, vm = mm * VX, lm = mm * LX, mw = mm * w; \
        a[0] += mm; a[1] += Gm;                                  \
        a[2] = fmaf(Gm, GX, a[2]); a[3] = fmaf(Gm, VX, a[3]);    \
        a[4] += vm; a[5] = fmaf(vm, VX, a[5]);                   \
        a[6] = fmaf(lm, GX, a[6]); a[7] += lm;                   \
        a[8] = fmaf(mm, ZX, a[8]); a[9] = fmaf(lm, VX, a[9]);    \
        C0X += mw;                                               \
        C1X = fmaf(mw, GX, C1X);                                 \
        C2X = fmaf(mw, w,  C2X);                                 \
        C3X = fmaf(mw, VX, C3X);                                 \
        C4X = fmaf(mw, LX, C4X);                                 \
    } while (0)

#define P1L(St, I_)                                                          \
    do {                                                                     \
        int e_ = base + (I_) * B4;                                           \
        r##St = rw[e_]; v##St = vv[e_]; l##St = lq[e_]; z##St = en[e_];      \
        if constexpr (I32) { q##St = ((const int4*)mp)[e_]; }                \
        else { uchar4 u_ = ((const uchar4*)mp)[e_];                          \
               q##St = make_int4(u_.x, u_.y, u_.z, u_.w); }                  \
    } while (0)

#define P1C(St)                                                              \
    do {                                                                     \
        COMPC((q##St.x ? 1.f : 0.f), G.x, r##St.x, v##St.x, l##St.x, z##St.x,\
              c0.x, c1.x, c2.x, c3.x, c4.x);                                 \
        COMPC((q##St.y ? 1.f : 0.f), G.y, r##St.y, v##St.y, l##St.y, z##St.y,\
              c0.y, c1.y, c2.y, c3.y, c4.y);                                 \
        COMPC((q##St.z ? 1.f : 0.f), G.z, r##St.z, v##St.z, l##St.z, z##St.z,\
              c0.z, c1.z, c2.z, c3.z, c4.z);                                 \
        COMPC((q##St.w ? 1.f : 0.f), G.w, r##St.w, v##St.w, l##St.w, z##St.w,\
              c0.w, c1.w, c2.w, c3.w, c4.w);                                 \
        w *= GAMMA_F;                                                        \
    } while (0)

template<bool I32>
__device__ __forceinline__ void pass1(const float4* __restrict__ rw,
                                      const float4* __restrict__ vv,
                                      const float4* __restrict__ lq,
                                      const float4* __restrict__ en,
                                      const void*  __restrict__ mp,
                                      int base, float4& G, float a[10],
                                      float4& c0, float4& c1, float4& c2,
                                      float4& c3, float4& c4) {
    float w = GAMMA_F;                 // gamma^(L-i), i = row index
    float4 rA, vA, lA, zA, rB, vB, lB, zB, rC, vC, lC, zC;
    int4 qA, qB, qC;
    P1L(A, 31); P1L(B, 30); P1L(C, 29);
    P1C(A); P1L(A, 28);   // row 31
    P1C(B); P1L(B, 27);   // row 30
    P1C(C); P1L(C, 26);   // row 29
    P1C(A); P1L(A, 25);   // row 28
    P1C(B); P1L(B, 24);   // row 27
    P1C(C); P1L(C, 23);   // row 26
    P1C(A); P1L(A, 22);   // row 25
    P1C(B); P1L(B, 21);   // row 24
    P1C(C); P1L(C, 20);   // row 23
    P1C(A); P1L(A, 19);   // row 22
    P1C(B); P1L(B, 18);   // row 21
    P1C(C); P1L(C, 17);   // row 20
    P1C(A); P1L(A, 16);   // row 19
    P1C(B); P1L(B, 15);   // row 18
    P1C(C); P1L(C, 14);   // row 17
    P1C(A); P1L(A, 13);   // row 16
    P1C(B); P1L(B, 12);   // row 15
    P1C(C); P1L(C, 11);   // row 14
    P1C(A); P1L(A, 10);   // row 13
    P1C(B); P1L(B, 9);    // row 12
    P1C(C); P1L(C, 8);    // row 11
    P1C(A); P1L(A, 7);    // row 10
    P1C(B); P1L(B, 6);    // row 9
    P1C(C); P1L(C, 5);    // row 8
    P1C(A); P1L(A, 4);    // row 7
    P1C(B); P1L(B, 3);    // row 6
    P1C(C); P1L(C, 2);    // row 5
    P1C(A); P1L(A, 1);    // row 4
    P1C(B); P1L(B, 0);    // row 3
    P1C(C);               // row 2
    P1C(A);               // row 1
    P1C(B);               // row 0
}

// --------------------------------------------------------------------------
__device__ __forceinline__ void finalize(const double s[10], float* out) {
    double n = s[0], SG = s[1], SG2 = s[2], SGv = s[3], Sv = s[4];
    double Sv2 = s[5], SlpG = s[6], Slp = s[7], Sent = s[8], Slpv = s[9];
    double mean = SG / n;
    double css  = SG2 - 2.0 * mean * SG + mean * mean * n;  // sum m*(G-mean)^2
    double var  = css / (n - 1.0);
    double sd   = sqrt(var);
    double sc   = 1.0 / (sd + 1e-8);
    double critic = sc * sc * css - 2.0 * sc * (SGv - mean * Sv) + Sv2;
    double actor  = -sc * (SlpG - mean * Slp) + Slpv - 0.01 * Sent;
    out[0] = (float)critic;
    out[1] = (float)actor;
}

__device__ __forceinline__ void reduce10_store(double d[10], double* dst,
                                               double shd[WAVES][10], int tid) {
    #pragma unroll
    for (int k = 0; k < 10; ++k)
        #pragma unroll
        for (int off = 32; off; off >>= 1)
            d[k] += __shfl_down(d[k], off);
    int lane = tid & 63, wv = tid >> 6;
    if (lane == 0) {
        #pragma unroll
        for (int k = 0; k < 10; ++k) shd[wv][k] = d[k];
    }
    __syncthreads();
    if (tid == 0) {
        #pragma unroll
        for (int k = 0; k < 10; ++k) {
            double t = shd[0][k];
            #pragma unroll
            for (int ww = 1; ww < WAVES; ++ww) t += shd[ww][k];
            dst[k] = t;
        }
    }
}

__device__ __forceinline__ void final_reduce(const double* __restrict__ p1,
                                             double shd[WAVES][10],
                                             int tid, float* out) {
    double d[10];
    #pragma unroll
    for (int k = 0; k < 10; ++k) d[k] = 0.0;
    for (int i = tid; i < NTILE; i += BLK) {
        #pragma unroll
        for (int k = 0; k < 10; ++k) d[k] += p1[(size_t)i * 10 + k];
    }
    #pragma unroll
    for (int k = 0; k < 10; ++k)
        #pragma unroll
        for (int off = 32; off; off >>= 1)
            d[k] += __shfl_down(d[k], off);
    int lane = tid & 63, wv = tid >> 6;
    if (lane == 0) {
        #pragma unroll
        for (int k = 0; k < 10; ++k) shd[wv][k] = d[k];
    }
    __syncthreads();
    if (tid == 0) {
        double s[10];
        #pragma unroll
        for (int k = 0; k < 10; ++k) {
            double t = shd[0][k];
            #pragma unroll
            for (int ww = 1; ww < WAVES; ++ww) t += shd[ww][k];
            s[k] = t;
        }
        finalize(s, out);
    }
}

// ==========================================================================
// Cooperative single-launch, single-pass kernel
__global__ void __launch_bounds__(BLK, 4) k_all(
    const float4* __restrict__ rw, const float4* __restrict__ vv,
    const float4* __restrict__ lq, const float4* __restrict__ en,
    const void*  __restrict__ mp,
    float4* __restrict__ S, float4* __restrict__ Sg, float4* __restrict__ Hg,
    double* __restrict__ p1, float* __restrict__ out)
{
    cg::grid_group grid = cg::this_grid();
    const int tid = threadIdx.x;
    const int bid = blockIdx.x;
    const int c = bid >> 2, s = bid & 3;
    const int b = s * 256 + tid;
    const int base = c * L * B4 + b;

    __shared__ double shd[WAVES][10];
    __shared__ unsigned shp[WAVES];

    // ---- probe: every block tests the same 16KB mask prefix.
    // int32 {0,1} layout: every aligned word & 0xFFFFFF00 == 0.
    unsigned pv = 0;
    {
        const uint4* mq = (const uint4*)mp;
        #pragma unroll
        for (int it = 0; it < 4; ++it) {
            uint4 q = mq[it * BLK + tid];
            pv |= (q.x | q.y | q.z | q.w) & 0xFFFFFF00u;
        }
        #pragma unroll
        for (int off = 32; off; off >>= 1) pv |= __shfl_down(pv, off);
        if ((tid & 63) == 0) shp[tid >> 6] = pv;
        __syncthreads();
        pv = shp[0] | shp[1] | shp[2] | shp[3];
    }
    const bool is32 = (pv == 0);

    // ---- phase 1: THE data pass (local G + correction coefficients)
    float4 G  = make_float4(0.f, 0.f, 0.f, 0.f);
    float4 c0 = G, c1 = G, c2 = G, c3 = G, c4 = G;
    float a[10] = {0.f, 0.f, 0.f, 0.f, 0.f, 0.f, 0.f, 0.f, 0.f, 0.f};
    if (is32) pass1<true >(rw, vv, lq, en, mp, base, G, a, c0, c1, c2, c3, c4);
    else      pass1<false>(rw, vv, lq, en, mp, base, G, a, c0, c1, c2, c3, c4);
    S[(size_t)c * B4 + b] = G;          // chunk sum = local G at row 0
    grid.sync();

    // ---- phase 2: group aggregates Sg[g] = sum_j G32^j S[16g+j] (64 blocks)
    if (bid < NGRP * B4 / BLK) {
        int idx = bid * BLK + tid;
        int g = idx >> 10;
        int bb = idx & 1023;
        float4 X = make_float4(0.f, 0.f, 0.f, 0.f);
        float w = 1.f;
        #pragma unroll
        for (int j = 0; j < GSZ; ++j) {
            float4 sv = S[(size_t)(g * GSZ + j) * B4 + bb];
            X.x = fmaf(w, sv.x, X.x); X.y = fmaf(w, sv.y, X.y);
            X.z = fmaf(w, sv.z, X.z); X.w = fmaf(w, sv.w, X.w);
            w *= G32;
        }
        Sg[(size_t)g * B4 + bb] = X;
    }
    grid.sync();

    // ---- phase 3: group carries Hg[g] = sum_{gg>g} G512^(gg-g-1) Sg[gg]
    if (bid < B4 / BLK) {
        int bb = bid * BLK + tid;
        float4 h = make_float4(0.f, 0.f, 0.f, 0.f);
        #pragma unroll
        for (int g = NGRP - 1; g >= 0; --g) {
            Hg[(size_t)g * B4 + bb] = h;
            float4 sv = Sg[(size_t)g * B4 + bb];
            h.x = fmaf(G512, h.x, sv.x); h.y = fmaf(G512, h.y, sv.y);
            h.z = fmaf(G512, h.z, sv.z); h.w = fmaf(G512, h.w, sv.w);
        }
    }
    grid.sync();

    // ---- phase 4: chunk carry + register corrections + block reduction
    {
        const int g = c >> 4;
        const int gend = (g << 4) | (GSZ - 1);
        float4 X = make_float4(0.f, 0.f, 0.f, 0.f);
        float w = 1.f;
        for (int cc = c + 1; cc <= gend; ++cc) {
            float4 sv = S[(size_t)cc * B4 + b];
            X.x = fmaf(w, sv.x, X.x); X.y = fmaf(w, sv.y, X.y);
            X.z = fmaf(w, sv.z, X.z); X.w = fmaf(w, sv.w, X.w);
            w *= G32;
        }
        float4 hg = Hg[(size_t)g * B4 + b];
        X.x = fmaf(w, hg.x, X.x); X.y = fmaf(w, hg.y, X.y);
        X.z = fmaf(w, hg.z, X.z); X.w = fmaf(w, hg.w, X.w);

        double d[10];
        #pragma unroll
        for (int k = 0; k < 10; ++k) d[k] = (double)a[k];
        double hx = X.x, hy = X.y, hz = X.z, hw = X.w;
        d[1] += hx * c0.x + hy * c0.y + hz * c0.z + hw * c0.w;
        d[2] += 2.0 * (hx * c1.x + hy * c1.y + hz * c1.z + hw * c1.w)
              + (hx * hx * c2.x + hy * hy * c2.y + hz * hz * c2.z + hw * hw * c2.w);
        d[3] += hx * c3.x + hy * c3.y + hz * c3.z + hw * c3.w;
        d[6] += hx * c4.x + hy * c4.y + hz * c4.z + hw * c4.w;

        reduce10_store(d, p1 + (size_t)bid * 10, shd, tid);
    }
    grid.sync();

    // ---- phase 5: final
    if (bid == 0) final_reduce(p1, shd, tid, out);
}

// ==========================================================================
// Fallback pipeline (4 dispatches) — r7-proven structure.
#define COMP(MJ, GX, RX, VX, LX, ZX)                 \
    do {                                             \
        GX = fmaf(GAMMA_F, GX, RX);                  \
        float mm = (MJ);                             \
        float Gm = mm * GX, vm = mm * VX, lm = mm * LX; \
        a[0] += mm; a[1] += Gm;                      \
        a[2] = fmaf(Gm, GX, a[2]);                   \
        a[3] = fmaf(Gm, VX, a[3]);                   \
        a[4] += vm; a[5] = fmaf(vm, VX, a[5]);       \
        a[6] = fmaf(lm, GX, a[6]); a[7] += lm;       \
        a[8] = fmaf(mm, ZX, a[8]);                   \
        a[9] = fmaf(lm, VX, a[9]);                   \
    } while (0)

#define MASK_I32 { int4 q = ((const int4*)mp)[e]; \
    m0 = q.x ? 1.f : 0.f; m1 = q.y ? 1.f : 0.f; m2 = q.z ? 1.f : 0.f; m3 = q.w ? 1.f : 0.f; }
#define MASK_U8  { uchar4 q = ((const uchar4*)mp)[e]; \
    m0 = q.x ? 1.f : 0.f; m1 = q.y ? 1.f : 0.f; m2 = q.z ? 1.f : 0.f; m3 = q.w ? 1.f : 0.f; }

#define ITER_BODY(MASKLOAD)                          \
    _Pragma("unroll 4")                              \
    for (int i = L - 1; i >= 0; --i) {               \
        int e = base + i * B4;                       \
        float4 r = rw[e], v = vv[e], l = lq[e], z = en[e]; \
        float m0, m1, m2, m3;                        \
        MASKLOAD;                                    \
        COMP(m0, G.x, r.x, v.x, l.x, z.x);           \
        COMP(m1, G.y, r.y, v.y, l.y, z.y);           \
        COMP(m2, G.z, r.z, v.z, l.z, z.z);           \
        COMP(m3, G.w, r.w, v.w, l.w, z.w);           \
    }

__device__ __forceinline__ float4 chunk_scan(const float4* __restrict__ rw, int base) {
    const float g2 = GAMMA_F * GAMMA_F;
    float4 e4 = make_float4(0.f, 0.f, 0.f, 0.f);
    float4 o4 = make_float4(0.f, 0.f, 0.f, 0.f);
    #pragma unroll
    for (int j = L / 2 - 1; j >= 0; --j) {
        float4 ro = rw[base + (2 * j + 1) * B4];
        float4 re = rw[base + (2 * j) * B4];
        o4.x = fmaf(g2, o4.x, ro.x); o4.y = fmaf(g2, o4.y, ro.y);
        o4.z = fmaf(g2, o4.z, ro.z); o4.w = fmaf(g2, o4.w, ro.w);
        e4.x = fmaf(g2, e4.x, re.x); e4.y = fmaf(g2, e4.y, re.y);
        e4.z = fmaf(g2, e4.z, re.z); e4.w = fmaf(g2, e4.w, re.w);
    }
    float4 s;
    s.x = fmaf(GAMMA_F, o4.x, e4.x); s.y = fmaf(GAMMA_F, o4.y, e4.y);
    s.z = fmaf(GAMMA_F, o4.z, e4.z); s.w = fmaf(GAMMA_F, o4.w, e4.w);
    return s;
}

__device__ __forceinline__ void mask_probe(const unsigned char* __restrict__ m8,
                                           unsigned shp[WAVES], int tid,
                                           int* __restrict__ dflag) {
    unsigned vbits = 0;
    for (int i = tid; i < 65536; i += BLK)
        if (i & 3) vbits |= m8[i];
    #pragma unroll
    for (int off = 32; off; off >>= 1) vbits |= __shfl_down(vbits, off);
    if ((tid & 63) == 0) shp[tid >> 6] = vbits;
    __syncthreads();
    if (tid == 0) {
        unsigned r = 0;
        #pragma unroll
        for (int w = 0; w < WAVES; ++w) r |= shp[w];
        *dflag = (r == 0) ? 1 : 0;
    }
}

__global__ void __launch_bounds__(BLK) k_scanf(const float4* __restrict__ rw,
                                               const void* __restrict__ mp,
                                               float4* __restrict__ S,
                                               int* __restrict__ dflag) {
    __shared__ unsigned shp[WAVES];
    const int tid = threadIdx.x, bid = blockIdx.x;
    const int c = bid >> 2, s = bid & 3;
    const int b = s * 256 + tid;
    S[(size_t)c * B4 + b] = chunk_scan(rw, c * L * B4 + b);
    if (bid == NTILE - 1) mask_probe((const unsigned char*)mp, shp, tid, dflag);
}

__global__ void __launch_bounds__(BLK) k_carryf(const float4* __restrict__ S,
                                                float4* __restrict__ H) {
    int col = blockIdx.x * BLK + threadIdx.x;
    float4 h = make_float4(0.f, 0.f, 0.f, 0.f);
    #pragma unroll 8
    for (int cc = NC - 1; cc >= 0; --cc) {
        H[(size_t)cc * B4 + col] = h;
        float4 s2 = S[(size_t)cc * B4 + col];
        h.x = fmaf(G32, h.x, s2.x); h.y = fmaf(G32, h.y, s2.y);
        h.z = fmaf(G32, h.z, s2.z); h.w = fmaf(G32, h.w, s2.w);
    }
}

__global__ void __launch_bounds__(BLK) k_mainf(const float4* __restrict__ rw,
                                               const float4* __restrict__ vv,
                                               const float4* __restrict__ lq,
                                               const float4* __restrict__ en,
                                               const void*  __restrict__ mp,
                                               const int*   __restrict__ dflag,
                                               const float4* __restrict__ H,
                                               double* __restrict__ p1) {
    __shared__ double shd[WAVES][10];
    const int tid = threadIdx.x, bid = blockIdx.x;
    const int c = bid >> 2, s = bid & 3;
    const int b = s * 256 + tid;
    const int base = c * L * B4 + b;
    float4 G = H[(size_t)c * B4 + b];
    float a[10] = {0.f, 0.f, 0.f, 0.f, 0.f, 0.f, 0.f, 0.f, 0.f, 0.f};
    if (*dflag) { ITER_BODY(MASK_I32); }
    else        { ITER_BODY(MASK_U8); }
    double d[10];
    #pragma unroll
    for (int k = 0; k < 10; ++k) d[k] = (double)a[k];
    reduce10_store(d, p1 + (size_t)bid * 10, shd, tid);
}

__global__ void __launch_bounds__(BLK) k_finalf(const double* __restrict__ p1,
                                                float* __restrict__ out) {
    __shared__ double shd[WAVES][10];
    final_reduce(p1, shd, threadIdx.x, out);
}

// ==========================================================================
extern "C" void kernel_launch(void* const* d_in, const int* in_sizes, int n_in,
                              void* d_out, int out_size, void* d_ws, size_t ws_size,
                              hipStream_t stream) {
    const float4* rw = (const float4*)d_in[0];
    const float4* vv = (const float4*)d_in[1];
    const float4* lq = (const float4*)d_in[2];
    const float4* en = (const float4*)d_in[3];
    const void*   mp = d_in[4];

    char* ws = (char*)d_ws;
    size_t off = 0;
    float4* S   = (float4*)(ws + off); off += (size_t)NC * B4 * 16;     // 4 MiB
    float4* Sg  = (float4*)(ws + off); off += (size_t)NGRP * B4 * 16;   // 256 KiB
    float4* Hg  = (float4*)(ws + off); off += (size_t)NGRP * B4 * 16;   // 256 KiB
    float4* H   = (float4*)(ws + off); off += (size_t)NC * B4 * 16;     // 4 MiB (fallback)
    double* p1  = (double*)(ws + off); off += (size_t)NTILE * 10 * 8;   // 80 KiB
    int*  dflag = (int*)  (ws + off);
    float* outp = (float*)d_out;

    int dev = 0;
    (void)hipGetDevice(&dev);
    int coop = 0, ncu = 0, maxb = 0;
    (void)hipDeviceGetAttribute(&coop, hipDeviceAttributeCooperativeLaunch, dev);
    (void)hipDeviceGetAttribute(&ncu, hipDeviceAttributeMultiprocessorCount, dev);
    bool use_coop = false;
    if (coop) {
        if (hipOccupancyMaxActiveBlocksPerMultiprocessor(&maxb, k_all, BLK, 0)
                == hipSuccess && (long)maxb * ncu >= NTILE)
            use_coop = true;
    }
    if (use_coop) {
        void* args[] = { (void*)&rw, (void*)&vv, (void*)&lq, (void*)&en,
                         (void*)&mp, (void*)&S, (void*)&Sg, (void*)&Hg,
                         (void*)&p1, (void*)&outp };
        if (hipLaunchCooperativeKernel((void*)k_all, dim3(NTILE), dim3(BLK),
                                       args, 0, stream) != hipSuccess)
            use_coop = false;
    }
    if (!use_coop) {
        k_scanf <<<NTILE, BLK, 0, stream>>>(rw, mp, S, dflag);
        k_carryf<<<B4 / BLK, BLK, 0, stream>>>(S, H);
        k_mainf <<<NTILE, BLK, 0, stream>>>(rw, vv, lq, en, mp, dflag, H, p1);
        k_finalf<<<1, BLK, 0, stream>>>(p1, outp);
    }
}

// Round 9
// 152.032 us; speedup vs baseline: 1.5365x; 1.5365x over previous
//
#include <hip/hip_runtime.h>
#include <hip/hip_cooperative_groups.h>

namespace cg = cooperative_groups;

// ---------------------------------------------------------------------------
// ActorCritic fused loss, MI355X.  T=8192, B=4096.
// ONE cooperative kernel, 4 grid.sync()s — all phases individually proven:
//   probe : all blocks test the same 16KB mask prefix (word&0xFFFFFF00)
//           -> int32 {0,1} vs 1-byte bool layout. Deterministic.
//   phase1: rewards -> chunk sums S[256][B4] (dual-chain Horner)   [r7: ~27us]
//   phase2: fold S -> 16 group aggregates Sg        (blocks 0..63) [r5: ~3us]
//   phase3: backward scan Sg -> group carries Hg    (blocks 0..3)  [r5: ~2us]
//   phase4: prologue folds <=15 S rows + Hg -> chunk carry; fused masked
//           pass over all 5 streams -> 10 block partials           [r5: 141us]
//   phase5: block 0 reduces partials, closed-form losses.
// No hand pipeline, no registers held across sync beyond loop-local state
// (r8 lesson: that spilled ~1GB of scratch traffic).
// Fallback (coop gate/launch refusal): same phases as 5 dispatches (r5-proven).
// All FP orders fixed -> bitwise deterministic across replays.
// ---------------------------------------------------------------------------

constexpr int T     = 8192;
constexpr int B     = 4096;
constexpr int B4    = B / 4;          // 1024 float4 columns
constexpr int BLK   = 256;
constexpr int WAVES = BLK / 64;
constexpr int L     = 32;             // chunk length
constexpr int NC    = T / L;          // 256 chunks
constexpr int NTILE = NC * 4;         // 1024 blocks (4 column slices)
constexpr int GSZ   = 16;             // chunks per group
constexpr int NGRP  = NC / GSZ;       // 16 groups

constexpr float GAMMA_F = 0.99f;
constexpr double cpow(double g, int n) { double r = 1.0; for (int i = 0; i < n; ++i) r *= g; return r; }
constexpr float G32  = (float)cpow(0.99, L);        // gamma^32
constexpr float G512 = (float)cpow(0.99, L * GSZ);  // gamma^512

// --------------------------------------------------------------------------
#define COMP(MJ, GX, RX, VX, LX, ZX)                 \
    do {                                             \
        GX = fmaf(GAMMA_F, GX, RX);                  \
        float mm = (MJ);                             \
        float Gm = mm * GX, vm = mm * VX, lm = mm * LX; \
        a[0] += mm; a[1] += Gm;                      \
        a[2] = fmaf(Gm, GX, a[2]);                   \
        a[3] = fmaf(Gm, VX, a[3]);                   \
        a[4] += vm; a[5] = fmaf(vm, VX, a[5]);       \
        a[6] = fmaf(lm, GX, a[6]); a[7] += lm;       \
        a[8] = fmaf(mm, ZX, a[8]);                   \
        a[9] = fmaf(lm, VX, a[9]);                   \
    } while (0)

#define MASK_I32 { int4 q = ((const int4*)mp)[e]; \
    m0 = q.x ? 1.f : 0.f; m1 = q.y ? 1.f : 0.f; m2 = q.z ? 1.f : 0.f; m3 = q.w ? 1.f : 0.f; }
#define MASK_U8  { uchar4 q = ((const uchar4*)mp)[e]; \
    m0 = q.x ? 1.f : 0.f; m1 = q.y ? 1.f : 0.f; m2 = q.z ? 1.f : 0.f; m3 = q.w ? 1.f : 0.f; }

#define ITER_BODY(MASKLOAD)                          \
    _Pragma("unroll 4")                              \
    for (int i = L - 1; i >= 0; --i) {               \
        int e = base + i * B4;                       \
        float4 r = rw[e], v = vv[e], l = lq[e], z = en[e]; \
        float m0, m1, m2, m3;                        \
        MASKLOAD;                                    \
        COMP(m0, G.x, r.x, v.x, l.x, z.x);           \
        COMP(m1, G.y, r.y, v.y, l.y, z.y);           \
        COMP(m2, G.z, r.z, v.z, l.z, z.z);           \
        COMP(m3, G.w, r.w, v.w, l.w, z.w);           \
    }

// dual-chain Horner over gamma^2 (half the dependent-FMA depth)
__device__ __forceinline__ float4 chunk_scan(const float4* __restrict__ rw, int base) {
    const float g2 = GAMMA_F * GAMMA_F;
    float4 e4 = make_float4(0.f, 0.f, 0.f, 0.f);
    float4 o4 = make_float4(0.f, 0.f, 0.f, 0.f);
    #pragma unroll
    for (int j = L / 2 - 1; j >= 0; --j) {
        float4 ro = rw[base + (2 * j + 1) * B4];
        float4 re = rw[base + (2 * j) * B4];
        o4.x = fmaf(g2, o4.x, ro.x); o4.y = fmaf(g2, o4.y, ro.y);
        o4.z = fmaf(g2, o4.z, ro.z); o4.w = fmaf(g2, o4.w, ro.w);
        e4.x = fmaf(g2, e4.x, re.x); e4.y = fmaf(g2, e4.y, re.y);
        e4.z = fmaf(g2, e4.z, re.z); e4.w = fmaf(g2, e4.w, re.w);
    }
    float4 s;
    s.x = fmaf(GAMMA_F, o4.x, e4.x); s.y = fmaf(GAMMA_F, o4.y, e4.y);
    s.z = fmaf(GAMMA_F, o4.z, e4.z); s.w = fmaf(GAMMA_F, o4.w, e4.w);
    return s;
}

// prologue: chunk-entry carry from S rows within group + group carry Hg
__device__ __forceinline__ float4 chunk_carry(const float4* __restrict__ S,
                                              const float4* __restrict__ Hg,
                                              int c, int b) {
    const int g = c >> 4;
    const int gend = (g << 4) | (GSZ - 1);
    float4 X = make_float4(0.f, 0.f, 0.f, 0.f);
    float w = 1.f;
    for (int cc = c + 1; cc <= gend; ++cc) {
        float4 sv = S[(size_t)cc * B4 + b];
        X.x = fmaf(w, sv.x, X.x); X.y = fmaf(w, sv.y, X.y);
        X.z = fmaf(w, sv.z, X.z); X.w = fmaf(w, sv.w, X.w);
        w *= G32;
    }
    float4 hg = Hg[(size_t)g * B4 + b];
    X.x = fmaf(w, hg.x, X.x); X.y = fmaf(w, hg.y, X.y);
    X.z = fmaf(w, hg.z, X.z); X.w = fmaf(w, hg.w, X.w);
    return X;
}

__device__ __forceinline__ void fold_groups(const float4* __restrict__ S,
                                            float4* __restrict__ Sg,
                                            int idx) {
    int g = idx >> 10;
    int bb = idx & 1023;
    float4 X = make_float4(0.f, 0.f, 0.f, 0.f);
    float w = 1.f;
    #pragma unroll
    for (int j = 0; j < GSZ; ++j) {
        float4 sv = S[(size_t)(g * GSZ + j) * B4 + bb];
        X.x = fmaf(w, sv.x, X.x); X.y = fmaf(w, sv.y, X.y);
        X.z = fmaf(w, sv.z, X.z); X.w = fmaf(w, sv.w, X.w);
        w *= G32;
    }
    Sg[(size_t)g * B4 + bb] = X;
}

__device__ __forceinline__ void gscan_col(const float4* __restrict__ Sg,
                                          float4* __restrict__ Hg, int bb) {
    float4 h = make_float4(0.f, 0.f, 0.f, 0.f);
    #pragma unroll
    for (int g = NGRP - 1; g >= 0; --g) {
        Hg[(size_t)g * B4 + bb] = h;
        float4 sv = Sg[(size_t)g * B4 + bb];
        h.x = fmaf(G512, h.x, sv.x); h.y = fmaf(G512, h.y, sv.y);
        h.z = fmaf(G512, h.z, sv.z); h.w = fmaf(G512, h.w, sv.w);
    }
}

// --------------------------------------------------------------------------
__device__ __forceinline__ void finalize(const double s[10], float* out) {
    double n = s[0], SG = s[1], SG2 = s[2], SGv = s[3], Sv = s[4];
    double Sv2 = s[5], SlpG = s[6], Slp = s[7], Sent = s[8], Slpv = s[9];
    double mean = SG / n;
    double css  = SG2 - 2.0 * mean * SG + mean * mean * n;  // sum m*(G-mean)^2
    double var  = css / (n - 1.0);
    double sd   = sqrt(var);
    double sc   = 1.0 / (sd + 1e-8);
    double critic = sc * sc * css - 2.0 * sc * (SGv - mean * Sv) + Sv2;
    double actor  = -sc * (SlpG - mean * Slp) + Slpv - 0.01 * Sent;
    out[0] = (float)critic;
    out[1] = (float)actor;
}

__device__ __forceinline__ void reduce10_store(double d[10], double* dst,
                                               double shd[WAVES][10], int tid) {
    #pragma unroll
    for (int k = 0; k < 10; ++k)
        #pragma unroll
        for (int off = 32; off; off >>= 1)
            d[k] += __shfl_down(d[k], off);
    int lane = tid & 63, wv = tid >> 6;
    if (lane == 0) {
        #pragma unroll
        for (int k = 0; k < 10; ++k) shd[wv][k] = d[k];
    }
    __syncthreads();
    if (tid == 0) {
        #pragma unroll
        for (int k = 0; k < 10; ++k) {
            double t = shd[0][k];
            #pragma unroll
            for (int ww = 1; ww < WAVES; ++ww) t += shd[ww][k];
            dst[k] = t;
        }
    }
}

__device__ __forceinline__ void final_reduce(const double* __restrict__ p1,
                                             double shd[WAVES][10],
                                             int tid, float* out) {
    double d[10];
    #pragma unroll
    for (int k = 0; k < 10; ++k) d[k] = 0.0;
    for (int i = tid; i < NTILE; i += BLK) {
        #pragma unroll
        for (int k = 0; k < 10; ++k) d[k] += p1[(size_t)i * 10 + k];
    }
    #pragma unroll
    for (int k = 0; k < 10; ++k)
        #pragma unroll
        for (int off = 32; off; off >>= 1)
            d[k] += __shfl_down(d[k], off);
    int lane = tid & 63, wv = tid >> 6;
    if (lane == 0) {
        #pragma unroll
        for (int k = 0; k < 10; ++k) shd[wv][k] = d[k];
    }
    __syncthreads();
    if (tid == 0) {
        double s[10];
        #pragma unroll
        for (int k = 0; k < 10; ++k) {
            double t = shd[0][k];
            #pragma unroll
            for (int ww = 1; ww < WAVES; ++ww) t += shd[ww][k];
            s[k] = t;
        }
        finalize(s, out);
    }
}

// ==========================================================================
// Cooperative single-launch kernel
__global__ void __launch_bounds__(BLK, 4) k_all(
    const float4* __restrict__ rw, const float4* __restrict__ vv,
    const float4* __restrict__ lq, const float4* __restrict__ en,
    const void*  __restrict__ mp,
    float4* __restrict__ S, float4* __restrict__ Sg, float4* __restrict__ Hg,
    double* __restrict__ p1, float* __restrict__ out)
{
    cg::grid_group grid = cg::this_grid();
    const int tid = threadIdx.x;
    const int bid = blockIdx.x;
    const int c = bid >> 2, s = bid & 3;
    const int b = s * 256 + tid;
    const int base = c * L * B4 + b;

    __shared__ double shd[WAVES][10];
    __shared__ unsigned shp[WAVES];

    // ---- probe: every block tests the same 16KB mask prefix.
    // int32 {0,1} layout: every aligned word & 0xFFFFFF00 == 0.
    unsigned pv = 0;
    {
        const uint4* mq = (const uint4*)mp;
        #pragma unroll
        for (int it = 0; it < 4; ++it) {
            uint4 q = mq[it * BLK + tid];
            pv |= (q.x | q.y | q.z | q.w) & 0xFFFFFF00u;
        }
        #pragma unroll
        for (int off = 32; off; off >>= 1) pv |= __shfl_down(pv, off);
        if ((tid & 63) == 0) shp[tid >> 6] = pv;
        __syncthreads();
        pv = shp[0] | shp[1] | shp[2] | shp[3];
    }
    const bool is32 = (pv == 0);

    // ---- phase 1: chunk sums
    S[(size_t)c * B4 + b] = chunk_scan(rw, base);
    grid.sync();

    // ---- phase 2: group aggregates (blocks 0..63)
    if (bid < NGRP * B4 / BLK) fold_groups(S, Sg, bid * BLK + tid);
    grid.sync();

    // ---- phase 3: group carries (blocks 0..3, 16 steps)
    if (bid < B4 / BLK) gscan_col(Sg, Hg, bid * BLK + tid);
    grid.sync();

    // ---- phase 4: carry prologue + fused masked pass
    {
        float4 G = chunk_carry(S, Hg, c, b);
        float a[10] = {0.f, 0.f, 0.f, 0.f, 0.f, 0.f, 0.f, 0.f, 0.f, 0.f};
        if (is32) { ITER_BODY(MASK_I32); }
        else      { ITER_BODY(MASK_U8); }
        double d[10];
        #pragma unroll
        for (int k = 0; k < 10; ++k) d[k] = (double)a[k];
        reduce10_store(d, p1 + (size_t)bid * 10, shd, tid);
    }
    grid.sync();

    // ---- phase 5: final
    if (bid == 0) final_reduce(p1, shd, tid, out);
}

// ==========================================================================
// Fallback pipeline (5 dispatches) — r5-proven structure.
__global__ void __launch_bounds__(BLK) k_scanf(const float4* __restrict__ rw,
                                               const void* __restrict__ mp,
                                               float4* __restrict__ S,
                                               int* __restrict__ dflag) {
    __shared__ unsigned shp[WAVES];
    const int tid = threadIdx.x, bid = blockIdx.x;
    const int c = bid >> 2, s = bid & 3;
    const int b = s * 256 + tid;
    S[(size_t)c * B4 + b] = chunk_scan(rw, c * L * B4 + b);
    if (bid == NTILE - 1) {
        unsigned pv = 0;
        const uint4* mq = (const uint4*)mp;
        #pragma unroll
        for (int it = 0; it < 4; ++it) {
            uint4 q = mq[it * BLK + tid];
            pv |= (q.x | q.y | q.z | q.w) & 0xFFFFFF00u;
        }
        #pragma unroll
        for (int off = 32; off; off >>= 1) pv |= __shfl_down(pv, off);
        if ((tid & 63) == 0) shp[tid >> 6] = pv;
        __syncthreads();
        if (tid == 0) *dflag = ((shp[0] | shp[1] | shp[2] | shp[3]) == 0) ? 1 : 0;
    }
}

__global__ void __launch_bounds__(BLK) k_foldf(const float4* __restrict__ S,
                                               float4* __restrict__ Sg) {
    fold_groups(S, Sg, blockIdx.x * BLK + threadIdx.x);
}

__global__ void __launch_bounds__(BLK) k_gscanf(const float4* __restrict__ Sg,
                                                float4* __restrict__ Hg) {
    gscan_col(Sg, Hg, blockIdx.x * BLK + threadIdx.x);
}

__global__ void __launch_bounds__(BLK) k_mainf(const float4* __restrict__ rw,
                                               const float4* __restrict__ vv,
                                               const float4* __restrict__ lq,
                                               const float4* __restrict__ en,
                                               const void*  __restrict__ mp,
                                               const int*   __restrict__ dflag,
                                               const float4* __restrict__ S,
                                               const float4* __restrict__ Hg,
                                               double* __restrict__ p1) {
    __shared__ double shd[WAVES][10];
    const int tid = threadIdx.x, bid = blockIdx.x;
    const int c = bid >> 2, s = bid & 3;
    const int b = s * 256 + tid;
    const int base = c * L * B4 + b;
    float4 G = chunk_carry(S, Hg, c, b);
    float a[10] = {0.f, 0.f, 0.f, 0.f, 0.f, 0.f, 0.f, 0.f, 0.f, 0.f};
    if (*dflag) { ITER_BODY(MASK_I32); }
    else        { ITER_BODY(MASK_U8); }
    double d[10];
    #pragma unroll
    for (int k = 0; k < 10; ++k) d[k] = (double)a[k];
    reduce10_store(d, p1 + (size_t)bid * 10, shd, tid);
}

__global__ void __launch_bounds__(BLK) k_finalf(const double* __restrict__ p1,
                                                float* __restrict__ out) {
    __shared__ double shd[WAVES][10];
    final_reduce(p1, shd, threadIdx.x, out);
}

// ==========================================================================
extern "C" void kernel_launch(void* const* d_in, const int* in_sizes, int n_in,
                              void* d_out, int out_size, void* d_ws, size_t ws_size,
                              hipStream_t stream) {
    const float4* rw = (const float4*)d_in[0];
    const float4* vv = (const float4*)d_in[1];
    const float4* lq = (const float4*)d_in[2];
    const float4* en = (const float4*)d_in[3];
    const void*   mp = d_in[4];

    char* ws = (char*)d_ws;
    size_t off = 0;
    float4* S   = (float4*)(ws + off); off += (size_t)NC * B4 * 16;     // 4 MiB
    float4* Sg  = (float4*)(ws + off); off += (size_t)NGRP * B4 * 16;   // 256 KiB
    float4* Hg  = (float4*)(ws + off); off += (size_t)NGRP * B4 * 16;   // 256 KiB
    double* p1  = (double*)(ws + off); off += (size_t)NTILE * 10 * 8;   // 80 KiB
    int*  dflag = (int*)  (ws + off);
    float* outp = (float*)d_out;

    int dev = 0;
    (void)hipGetDevice(&dev);
    int coop = 0, ncu = 0, maxb = 0;
    (void)hipDeviceGetAttribute(&coop, hipDeviceAttributeCooperativeLaunch, dev);
    (void)hipDeviceGetAttribute(&ncu, hipDeviceAttributeMultiprocessorCount, dev);
    bool use_coop = false;
    if (coop) {
        if (hipOccupancyMaxActiveBlocksPerMultiprocessor(&maxb, k_all, BLK, 0)
                == hipSuccess && (long)maxb * ncu >= NTILE)
            use_coop = true;
    }
    if (use_coop) {
        void* args[] = { (void*)&rw, (void*)&vv, (void*)&lq, (void*)&en,
                         (void*)&mp, (void*)&S, (void*)&Sg, (void*)&Hg,
                         (void*)&p1, (void*)&outp };
        if (hipLaunchCooperativeKernel((void*)k_all, dim3(NTILE), dim3(BLK),
                                       args, 0, stream) != hipSuccess)
            use_coop = false;
    }
    if (!use_coop) {
        k_scanf <<<NTILE, BLK, 0, stream>>>(rw, mp, S, dflag);
        k_foldf <<<NGRP * B4 / BLK, BLK, 0, stream>>>(S, Sg);
        k_gscanf<<<B4 / BLK, BLK, 0, stream>>>(Sg, Hg);
        k_mainf <<<NTILE, BLK, 0, stream>>>(rw, vv, lq, en, mp, dflag, S, Hg, p1);
        k_finalf<<<1, BLK, 0, stream>>>(p1, outp);
    }
}

// Round 10
// 150.328 us; speedup vs baseline: 1.5539x; 1.0113x over previous
//
#include <hip/hip_runtime.h>
#include <hip/hip_cooperative_groups.h>

namespace cg = cooperative_groups;

// ---------------------------------------------------------------------------
// ActorCritic fused loss, MI355X.  T=8192, B=4096.
// ONE cooperative kernel, ONE pass over the big data:
//   probe  : all blocks test the same 16KB mask prefix (word&0xFFFFFF00)
//            -> int32 {0,1} vs 1-byte bool layout. Deterministic.
//   phase1 : single fused pass over all 5 streams with LOCAL G.
//            Accumulates 10 base sums (block-reduced to p1 immediately) and
//            5 carry-correction coefficient float4s, which are WRITTEN TO
//            WORKSPACE (20 MB) — not held in registers across sync
//            (r8 lesson: that spilled ~1 GB of scratch traffic).
//            Also writes chunk sums S (local G at row 0).
//   phase2 : fold S -> 16 group aggregates Sg      (blocks 0..63)
//   phase3 : backward scan Sg -> group carries Hg  (blocks 0..3, 16 steps)
//   phase4 : per thread: chunk carry H from <=15 S rows + Hg; load coeffs;
//            f64 corrections dSG=H*c0, dSG2=2H*c1+H^2*c2, dSGv=H*c3,
//            dSlpG=H*c4; block-reduce 4 deltas -> p2.
//   phase5 : block 0 reduces p1 + p2, closed-form losses.
// Correction algebra verified in r2/r8 (absmax 0 both).
// Fallback (coop gate/launch refusal): r9-proven 5-dispatch pipeline.
// All FP orders fixed -> bitwise deterministic across replays.
// ---------------------------------------------------------------------------

constexpr int T     = 8192;
constexpr int B     = 4096;
constexpr int B4    = B / 4;          // 1024 float4 columns
constexpr int BLK   = 256;
constexpr int WAVES = BLK / 64;
constexpr int L     = 32;             // chunk length
constexpr int NC    = T / L;          // 256 chunks
constexpr int NTILE = NC * 4;         // 1024 blocks (4 column slices)
constexpr int GSZ   = 16;             // chunks per group
constexpr int NGRP  = NC / GSZ;       // 16 groups
constexpr int NTHR  = NTILE * BLK;    // 262144 threads

constexpr float GAMMA_F = 0.99f;
constexpr double cpow(double g, int n) { double r = 1.0; for (int i = 0; i < n; ++i) r *= g; return r; }
constexpr float G32  = (float)cpow(0.99, L);        // gamma^32
constexpr float G512 = (float)cpow(0.99, L * GSZ);  // gamma^512

// --------------------------------------------------------------------------
// fused accumulate: 10 base sums (local G) + 5 correction coefficients.
// w = gamma^(L-i) for row i (carry weight).
#define COMPC(MJ, GX, RX, VX, LX, ZX, C0X, C1X, C2X, C3X, C4X)   \
    do {                                                         \
        GX = fmaf(GAMMA_F, GX, RX);                              \
        float mm = (MJ);                                         \
        float Gm = mm * GX, vm = mm * VX, lm = mm * LX, mw = mm * w; \
        a[0] += mm; a[1] += Gm;                                  \
        a[2] = fmaf(Gm, GX, a[2]); a[3] = fmaf(Gm, VX, a[3]);    \
        a[4] += vm; a[5] = fmaf(vm, VX, a[5]);                   \
        a[6] = fmaf(lm, GX, a[6]); a[7] += lm;                   \
        a[8] = fmaf(mm, ZX, a[8]); a[9] = fmaf(lm, VX, a[9]);    \
        C0X += mw;                                               \
        C1X = fmaf(mw, GX, C1X);                                 \
        C2X = fmaf(mw, w,  C2X);                                 \
        C3X = fmaf(mw, VX, C3X);                                 \
        C4X = fmaf(mw, LX, C4X);                                 \
    } while (0)

#define MASK_I32 { int4 q = ((const int4*)mp)[e]; \
    m0 = q.x ? 1.f : 0.f; m1 = q.y ? 1.f : 0.f; m2 = q.z ? 1.f : 0.f; m3 = q.w ? 1.f : 0.f; }
#define MASK_U8  { uchar4 q = ((const uchar4*)mp)[e]; \
    m0 = q.x ? 1.f : 0.f; m1 = q.y ? 1.f : 0.f; m2 = q.z ? 1.f : 0.f; m3 = q.w ? 1.f : 0.f; }

#define ITER_BODYC(MASKLOAD)                         \
    _Pragma("unroll 4")                              \
    for (int i = L - 1; i >= 0; --i) {               \
        int e = base + i * B4;                       \
        float4 r = rw[e], v = vv[e], l = lq[e], z = en[e]; \
        float m0, m1, m2, m3;                        \
        MASKLOAD;                                    \
        COMPC(m0, G.x, r.x, v.x, l.x, z.x, c0.x, c1.x, c2.x, c3.x, c4.x); \
        COMPC(m1, G.y, r.y, v.y, l.y, z.y, c0.y, c1.y, c2.y, c3.y, c4.y); \
        COMPC(m2, G.z, r.z, v.z, l.z, z.z, c0.z, c1.z, c2.z, c3.z, c4.z); \
        COMPC(m3, G.w, r.w, v.w, l.w, z.w, c0.w, c1.w, c2.w, c3.w, c4.w); \
        w *= GAMMA_F;                                \
    }

// plain 10-sum body (fallback path)
#define COMP(MJ, GX, RX, VX, LX, ZX)                 \
    do {                                             \
        GX = fmaf(GAMMA_F, GX, RX);                  \
        float mm = (MJ);                             \
        float Gm = mm * GX, vm = mm * VX, lm = mm * LX; \
        a[0] += mm; a[1] += Gm;                      \
        a[2] = fmaf(Gm, GX, a[2]);                   \
        a[3] = fmaf(Gm, VX, a[3]);                   \
        a[4] += vm; a[5] = fmaf(vm, VX, a[5]);       \
        a[6] = fmaf(lm, GX, a[6]); a[7] += lm;       \
        a[8] = fmaf(mm, ZX, a[8]);                   \
        a[9] = fmaf(lm, VX, a[9]);                   \
    } while (0)

#define ITER_BODY(MASKLOAD)                          \
    _Pragma("unroll 4")                              \
    for (int i = L - 1; i >= 0; --i) {               \
        int e = base + i * B4;                       \
        float4 r = rw[e], v = vv[e], l = lq[e], z = en[e]; \
        float m0, m1, m2, m3;                        \
        MASKLOAD;                                    \
        COMP(m0, G.x, r.x, v.x, l.x, z.x);           \
        COMP(m1, G.y, r.y, v.y, l.y, z.y);           \
        COMP(m2, G.z, r.z, v.z, l.z, z.z);           \
        COMP(m3, G.w, r.w, v.w, l.w, z.w);           \
    }

// --------------------------------------------------------------------------
__device__ __forceinline__ float4 chunk_scan(const float4* __restrict__ rw, int base) {
    const float g2 = GAMMA_F * GAMMA_F;
    float4 e4 = make_float4(0.f, 0.f, 0.f, 0.f);
    float4 o4 = make_float4(0.f, 0.f, 0.f, 0.f);
    #pragma unroll
    for (int j = L / 2 - 1; j >= 0; --j) {
        float4 ro = rw[base + (2 * j + 1) * B4];
        float4 re = rw[base + (2 * j) * B4];
        o4.x = fmaf(g2, o4.x, ro.x); o4.y = fmaf(g2, o4.y, ro.y);
        o4.z = fmaf(g2, o4.z, ro.z); o4.w = fmaf(g2, o4.w, ro.w);
        e4.x = fmaf(g2, e4.x, re.x); e4.y = fmaf(g2, e4.y, re.y);
        e4.z = fmaf(g2, e4.z, re.z); e4.w = fmaf(g2, e4.w, re.w);
    }
    float4 s;
    s.x = fmaf(GAMMA_F, o4.x, e4.x); s.y = fmaf(GAMMA_F, o4.y, e4.y);
    s.z = fmaf(GAMMA_F, o4.z, e4.z); s.w = fmaf(GAMMA_F, o4.w, e4.w);
    return s;
}

__device__ __forceinline__ float4 chunk_carry(const float4* __restrict__ S,
                                              const float4* __restrict__ Hg,
                                              int c, int b) {
    const int g = c >> 4;
    const int gend = (g << 4) | (GSZ - 1);
    float4 X = make_float4(0.f, 0.f, 0.f, 0.f);
    float w = 1.f;
    for (int cc = c + 1; cc <= gend; ++cc) {
        float4 sv = S[(size_t)cc * B4 + b];
        X.x = fmaf(w, sv.x, X.x); X.y = fmaf(w, sv.y, X.y);
        X.z = fmaf(w, sv.z, X.z); X.w = fmaf(w, sv.w, X.w);
        w *= G32;
    }
    float4 hg = Hg[(size_t)g * B4 + b];
    X.x = fmaf(w, hg.x, X.x); X.y = fmaf(w, hg.y, X.y);
    X.z = fmaf(w, hg.z, X.z); X.w = fmaf(w, hg.w, X.w);
    return X;
}

__device__ __forceinline__ void fold_groups(const float4* __restrict__ S,
                                            float4* __restrict__ Sg, int idx) {
    int g = idx >> 10;
    int bb = idx & 1023;
    float4 X = make_float4(0.f, 0.f, 0.f, 0.f);
    float w = 1.f;
    #pragma unroll
    for (int j = 0; j < GSZ; ++j) {
        float4 sv = S[(size_t)(g * GSZ + j) * B4 + bb];
        X.x = fmaf(w, sv.x, X.x); X.y = fmaf(w, sv.y, X.y);
        X.z = fmaf(w, sv.z, X.z); X.w = fmaf(w, sv.w, X.w);
        w *= G32;
    }
    Sg[(size_t)g * B4 + bb] = X;
}

__device__ __forceinline__ void gscan_col(const float4* __restrict__ Sg,
                                          float4* __restrict__ Hg, int bb) {
    float4 h = make_float4(0.f, 0.f, 0.f, 0.f);
    #pragma unroll
    for (int g = NGRP - 1; g >= 0; --g) {
        Hg[(size_t)g * B4 + bb] = h;
        float4 sv = Sg[(size_t)g * B4 + bb];
        h.x = fmaf(G512, h.x, sv.x); h.y = fmaf(G512, h.y, sv.y);
        h.z = fmaf(G512, h.z, sv.z); h.w = fmaf(G512, h.w, sv.w);
    }
}

// --------------------------------------------------------------------------
__device__ __forceinline__ void finalize(const double s[10], float* out) {
    double n = s[0], SG = s[1], SG2 = s[2], SGv = s[3], Sv = s[4];
    double Sv2 = s[5], SlpG = s[6], Slp = s[7], Sent = s[8], Slpv = s[9];
    double mean = SG / n;
    double css  = SG2 - 2.0 * mean * SG + mean * mean * n;  // sum m*(G-mean)^2
    double var  = css / (n - 1.0);
    double sd   = sqrt(var);
    double sc   = 1.0 / (sd + 1e-8);
    double critic = sc * sc * css - 2.0 * sc * (SGv - mean * Sv) + Sv2;
    double actor  = -sc * (SlpG - mean * Slp) + Slpv - 0.01 * Sent;
    out[0] = (float)critic;
    out[1] = (float)actor;
}

__device__ __forceinline__ void reduce10_store(double d[10], double* dst,
                                               double shd[WAVES][10], int tid) {
    #pragma unroll
    for (int k = 0; k < 10; ++k)
        #pragma unroll
        for (int off = 32; off; off >>= 1)
            d[k] += __shfl_down(d[k], off);
    int lane = tid & 63, wv = tid >> 6;
    if (lane == 0) {
        #pragma unroll
        for (int k = 0; k < 10; ++k) shd[wv][k] = d[k];
    }
    __syncthreads();
    if (tid == 0) {
        #pragma unroll
        for (int k = 0; k < 10; ++k) {
            double t = shd[0][k];
            #pragma unroll
            for (int ww = 1; ww < WAVES; ++ww) t += shd[ww][k];
            dst[k] = t;
        }
    }
}

__device__ __forceinline__ void reduce4_store(double d[4], double* dst,
                                              double shd[WAVES][10], int tid) {
    #pragma unroll
    for (int k = 0; k < 4; ++k)
        #pragma unroll
        for (int off = 32; off; off >>= 1)
            d[k] += __shfl_down(d[k], off);
    int lane = tid & 63, wv = tid >> 6;
    if (lane == 0) {
        #pragma unroll
        for (int k = 0; k < 4; ++k) shd[wv][k] = d[k];
    }
    __syncthreads();
    if (tid == 0) {
        #pragma unroll
        for (int k = 0; k < 4; ++k) {
            double t = shd[0][k];
            #pragma unroll
            for (int ww = 1; ww < WAVES; ++ww) t += shd[ww][k];
            dst[k] = t;
        }
    }
}

// ==========================================================================
// Cooperative single-launch, single-pass kernel
__global__ void __launch_bounds__(BLK, 4) k_all(
    const float4* __restrict__ rw, const float4* __restrict__ vv,
    const float4* __restrict__ lq, const float4* __restrict__ en,
    const void*  __restrict__ mp,
    float4* __restrict__ S, float4* __restrict__ Sg, float4* __restrict__ Hg,
    float4* __restrict__ CF0, float4* __restrict__ CF1, float4* __restrict__ CF2,
    float4* __restrict__ CF3, float4* __restrict__ CF4,
    double* __restrict__ p1, double* __restrict__ p2, float* __restrict__ out)
{
    cg::grid_group grid = cg::this_grid();
    const int tid = threadIdx.x;
    const int bid = blockIdx.x;
    const int c = bid >> 2, s = bid & 3;
    const int b = s * 256 + tid;
    const int base = c * L * B4 + b;
    const size_t gt = (size_t)bid * BLK + tid;

    __shared__ double shd[WAVES][10];
    __shared__ unsigned shp[WAVES];

    // ---- probe: every block tests the same 16KB mask prefix.
    unsigned pv = 0;
    {
        const uint4* mq = (const uint4*)mp;
        #pragma unroll
        for (int it = 0; it < 4; ++it) {
            uint4 q = mq[it * BLK + tid];
            pv |= (q.x | q.y | q.z | q.w) & 0xFFFFFF00u;
        }
        #pragma unroll
        for (int off = 32; off; off >>= 1) pv |= __shfl_down(pv, off);
        if ((tid & 63) == 0) shp[tid >> 6] = pv;
        __syncthreads();
        pv = shp[0] | shp[1] | shp[2] | shp[3];
    }
    const bool is32 = (pv == 0);

    // ---- phase 1: THE single pass (10 base sums + 5 coeffs -> memory)
    {
        float4 G  = make_float4(0.f, 0.f, 0.f, 0.f);
        float4 c0 = G, c1 = G, c2 = G, c3 = G, c4 = G;
        float a[10] = {0.f, 0.f, 0.f, 0.f, 0.f, 0.f, 0.f, 0.f, 0.f, 0.f};
        float w = GAMMA_F;
        if (is32) { ITER_BODYC(MASK_I32); }
        else      { ITER_BODYC(MASK_U8); }

        S[(size_t)c * B4 + b] = G;       // chunk sum = local G at row 0
        CF0[gt] = c0; CF1[gt] = c1; CF2[gt] = c2; CF3[gt] = c3; CF4[gt] = c4;

        double d[10];
        #pragma unroll
        for (int k = 0; k < 10; ++k) d[k] = (double)a[k];
        reduce10_store(d, p1 + (size_t)bid * 10, shd, tid);
    }
    grid.sync();

    // ---- phase 2: group aggregates (blocks 0..63)
    if (bid < NGRP * B4 / BLK) fold_groups(S, Sg, bid * BLK + tid);
    grid.sync();

    // ---- phase 3: group carries (blocks 0..3, 16 steps)
    if (bid < B4 / BLK) gscan_col(Sg, Hg, bid * BLK + tid);
    grid.sync();

    // ---- phase 4: corrections from chunk carry + stored coeffs
    {
        float4 X = chunk_carry(S, Hg, c, b);
        float4 c0 = CF0[gt], c1 = CF1[gt], c2 = CF2[gt], c3 = CF3[gt], c4 = CF4[gt];
        double hx = X.x, hy = X.y, hz = X.z, hw = X.w;
        double d[4];
        d[0] = hx * c0.x + hy * c0.y + hz * c0.z + hw * c0.w;               // dSG
        d[1] = 2.0 * (hx * c1.x + hy * c1.y + hz * c1.z + hw * c1.w)
             + (hx * hx * c2.x + hy * hy * c2.y + hz * hz * c2.z + hw * hw * c2.w); // dSG2
        d[2] = hx * c3.x + hy * c3.y + hz * c3.z + hw * c3.w;               // dSGv
        d[3] = hx * c4.x + hy * c4.y + hz * c4.z + hw * c4.w;               // dSlpG
        reduce4_store(d, p2 + (size_t)bid * 4, shd, tid);
    }
    grid.sync();

    // ---- phase 5: final (block 0)
    if (bid == 0) {
        double d[10];
        #pragma unroll
        for (int k = 0; k < 10; ++k) d[k] = 0.0;
        for (int i = tid; i < NTILE; i += BLK) {
            #pragma unroll
            for (int k = 0; k < 10; ++k) d[k] += p1[(size_t)i * 10 + k];
            d[1] += p2[(size_t)i * 4 + 0];
            d[2] += p2[(size_t)i * 4 + 1];
            d[3] += p2[(size_t)i * 4 + 2];
            d[6] += p2[(size_t)i * 4 + 3];
        }
        #pragma unroll
        for (int k = 0; k < 10; ++k)
            #pragma unroll
            for (int off = 32; off; off >>= 1)
                d[k] += __shfl_down(d[k], off);
        int lane = tid & 63, wv = tid >> 6;
        if (lane == 0) {
            #pragma unroll
            for (int k = 0; k < 10; ++k) shd[wv][k] = d[k];
        }
        __syncthreads();
        if (tid == 0) {
            double sum[10];
            #pragma unroll
            for (int k = 0; k < 10; ++k) {
                double t = shd[0][k];
                #pragma unroll
                for (int ww = 1; ww < WAVES; ++ww) t += shd[ww][k];
                sum[k] = t;
            }
            finalize(sum, out);
        }
    }
}

// ==========================================================================
// Fallback pipeline (5 dispatches) — r9-proven structure.
__global__ void __launch_bounds__(BLK) k_scanf(const float4* __restrict__ rw,
                                               const void* __restrict__ mp,
                                               float4* __restrict__ S,
                                               int* __restrict__ dflag) {
    __shared__ unsigned shp[WAVES];
    const int tid = threadIdx.x, bid = blockIdx.x;
    const int c = bid >> 2, s = bid & 3;
    const int b = s * 256 + tid;
    S[(size_t)c * B4 + b] = chunk_scan(rw, c * L * B4 + b);
    if (bid == NTILE - 1) {
        unsigned pv = 0;
        const uint4* mq = (const uint4*)mp;
        #pragma unroll
        for (int it = 0; it < 4; ++it) {
            uint4 q = mq[it * BLK + tid];
            pv |= (q.x | q.y | q.z | q.w) & 0xFFFFFF00u;
        }
        #pragma unroll
        for (int off = 32; off; off >>= 1) pv |= __shfl_down(pv, off);
        if ((tid & 63) == 0) shp[tid >> 6] = pv;
        __syncthreads();
        if (tid == 0) *dflag = ((shp[0] | shp[1] | shp[2] | shp[3]) == 0) ? 1 : 0;
    }
}

__global__ void __launch_bounds__(BLK) k_foldf(const float4* __restrict__ S,
                                               float4* __restrict__ Sg) {
    fold_groups(S, Sg, blockIdx.x * BLK + threadIdx.x);
}

__global__ void __launch_bounds__(BLK) k_gscanf(const float4* __restrict__ Sg,
                                                float4* __restrict__ Hg) {
    gscan_col(Sg, Hg, blockIdx.x * BLK + threadIdx.x);
}

__global__ void __launch_bounds__(BLK) k_mainf(const float4* __restrict__ rw,
                                               const float4* __restrict__ vv,
                                               const float4* __restrict__ lq,
                                               const float4* __restrict__ en,
                                               const void*  __restrict__ mp,
                                               const int*   __restrict__ dflag,
                                               const float4* __restrict__ S,
                                               const float4* __restrict__ Hg,
                                               double* __restrict__ p1) {
    __shared__ double shd[WAVES][10];
    const int tid = threadIdx.x, bid = blockIdx.x;
    const int c = bid >> 2, s = bid & 3;
    const int b = s * 256 + tid;
    const int base = c * L * B4 + b;
    float4 G = chunk_carry(S, Hg, c, b);
    float a[10] = {0.f, 0.f, 0.f, 0.f, 0.f, 0.f, 0.f, 0.f, 0.f, 0.f};
    if (*dflag) { ITER_BODY(MASK_I32); }
    else        { ITER_BODY(MASK_U8); }
    double d[10];
    #pragma unroll
    for (int k = 0; k < 10; ++k) d[k] = (double)a[k];
    reduce10_store(d, p1 + (size_t)bid * 10, shd, tid);
}

__global__ void __launch_bounds__(BLK) k_finalf(const double* __restrict__ p1,
                                                float* __restrict__ out) {
    __shared__ double shd[WAVES][10];
    const int tid = threadIdx.x;
    double d[10];
    #pragma unroll
    for (int k = 0; k < 10; ++k) d[k] = 0.0;
    for (int i = tid; i < NTILE; i += BLK) {
        #pragma unroll
        for (int k = 0; k < 10; ++k) d[k] += p1[(size_t)i * 10 + k];
    }
    #pragma unroll
    for (int k = 0; k < 10; ++k)
        #pragma unroll
        for (int off = 32; off; off >>= 1)
            d[k] += __shfl_down(d[k], off);
    int lane = tid & 63, wv = tid >> 6;
    if (lane == 0) {
        #pragma unroll
        for (int k = 0; k < 10; ++k) shd[wv][k] = d[k];
    }
    __syncthreads();
    if (tid == 0) {
        double s[10];
        #pragma unroll
        for (int k = 0; k < 10; ++k) {
            double t = shd[0][k];
            #pragma unroll
            for (int ww = 1; ww < WAVES; ++ww) t += shd[ww][k];
            s[k] = t;
        }
        finalize(s, out);
    }
}

// ==========================================================================
extern "C" void kernel_launch(void* const* d_in, const int* in_sizes, int n_in,
                              void* d_out, int out_size, void* d_ws, size_t ws_size,
                              hipStream_t stream) {
    const float4* rw = (const float4*)d_in[0];
    const float4* vv = (const float4*)d_in[1];
    const float4* lq = (const float4*)d_in[2];
    const float4* en = (const float4*)d_in[3];
    const void*   mp = d_in[4];

    char* ws = (char*)d_ws;
    size_t off = 0;
    float4* S   = (float4*)(ws + off); off += (size_t)NC * B4 * 16;     // 4 MiB
    float4* Sg  = (float4*)(ws + off); off += (size_t)NGRP * B4 * 16;   // 256 KiB
    float4* Hg  = (float4*)(ws + off); off += (size_t)NGRP * B4 * 16;   // 256 KiB
    float4* CF0 = (float4*)(ws + off); off += (size_t)NTHR * 16;        // 4 MiB
    float4* CF1 = (float4*)(ws + off); off += (size_t)NTHR * 16;        // 4 MiB
    float4* CF2 = (float4*)(ws + off); off += (size_t)NTHR * 16;        // 4 MiB
    float4* CF3 = (float4*)(ws + off); off += (size_t)NTHR * 16;        // 4 MiB
    float4* CF4 = (float4*)(ws + off); off += (size_t)NTHR * 16;        // 4 MiB
    double* p1  = (double*)(ws + off); off += (size_t)NTILE * 10 * 8;   // 80 KiB
    double* p2  = (double*)(ws + off); off += (size_t)NTILE * 4 * 8;    // 32 KiB
    int*  dflag = (int*)  (ws + off);
    float* outp = (float*)d_out;

    int dev = 0;
    (void)hipGetDevice(&dev);
    int coop = 0, ncu = 0, maxb = 0;
    (void)hipDeviceGetAttribute(&coop, hipDeviceAttributeCooperativeLaunch, dev);
    (void)hipDeviceGetAttribute(&ncu, hipDeviceAttributeMultiprocessorCount, dev);
    bool use_coop = false;
    if (coop) {
        if (hipOccupancyMaxActiveBlocksPerMultiprocessor(&maxb, k_all, BLK, 0)
                == hipSuccess && (long)maxb * ncu >= NTILE)
            use_coop = true;
    }
    if (use_coop) {
        void* args[] = { (void*)&rw, (void*)&vv, (void*)&lq, (void*)&en,
                         (void*)&mp, (void*)&S, (void*)&Sg, (void*)&Hg,
                         (void*)&CF0, (void*)&CF1, (void*)&CF2, (void*)&CF3,
                         (void*)&CF4, (void*)&p1, (void*)&p2, (void*)&outp };
        if (hipLaunchCooperativeKernel((void*)k_all, dim3(NTILE), dim3(BLK),
                                       args, 0, stream) != hipSuccess)
            use_coop = false;
    }
    if (!use_coop) {
        k_scanf <<<NTILE, BLK, 0, stream>>>(rw, mp, S, dflag);
        k_foldf <<<NGRP * B4 / BLK, BLK, 0, stream>>>(S, Sg);
        k_gscanf<<<B4 / BLK, BLK, 0, stream>>>(Sg, Hg);
        k_mainf <<<NTILE, BLK, 0, stream>>>(rw, vv, lq, en, mp, dflag, S, Hg, p1);
        k_finalf<<<1, BLK, 0, stream>>>(p1, outp);
    }
}